// Round 21
// baseline (9430.676 us; speedup 1.0000x reference)
//
#include <hip/hip_runtime.h>

#define S_LEN 2048
#define HID   4096
#define NH    32
#define NKV   8
#define HD    128
#define KVDIM (NKV * HD)

// ---------------- fp32 GEMM-BT: C[m][n] = sum_k A[m][k]*B[n][k] ----------------
__global__ __launch_bounds__(256) void k_gemm_f32(const float* __restrict__ A,
                                                  const float* __restrict__ B,
                                                  float* __restrict__ C,
                                                  int M, int N, int K) {
  __shared__ float As[128][17];
  __shared__ float Bs[64][17];
  const int t = threadIdx.x;
  const int tx = t & 15, ty = t >> 4;
  const int m0 = blockIdx.x * 128, n0 = blockIdx.y * 64;

  float acc[8][4];
#pragma unroll
  for (int i = 0; i < 8; ++i)
#pragma unroll
    for (int j = 0; j < 4; ++j) acc[i][j] = 0.f;

  for (int kt = 0; kt < K; kt += 16) {
    __syncthreads();
#pragma unroll
    for (int q = 0; q < 2; ++q) {
      int c = q * 256 + t;
      int row = c >> 2, k4 = (c & 3) * 4;
      float4 v = *(const float4*)(A + (size_t)(m0 + row) * K + kt + k4);
      As[row][k4] = v.x; As[row][k4 + 1] = v.y; As[row][k4 + 2] = v.z; As[row][k4 + 3] = v.w;
    }
    {
      int row = t >> 2, k4 = (t & 3) * 4;
      float4 v = *(const float4*)(B + (size_t)(n0 + row) * K + kt + k4);
      Bs[row][k4] = v.x; Bs[row][k4 + 1] = v.y; Bs[row][k4 + 2] = v.z; Bs[row][k4 + 3] = v.w;
    }
    __syncthreads();

#pragma unroll
    for (int k = 0; k < 16; ++k) {
      float a[8], b[4];
#pragma unroll
      for (int i = 0; i < 8; ++i) a[i] = As[ty * 8 + i][k];
#pragma unroll
      for (int j = 0; j < 4; ++j) b[j] = Bs[tx * 4 + j][k];
#pragma unroll
      for (int i = 0; i < 8; ++i)
#pragma unroll
        for (int j = 0; j < 4; ++j) acc[i][j] = fmaf(a[i], b[j], acc[i][j]);
    }
  }

#pragma unroll
  for (int i = 0; i < 8; ++i)
#pragma unroll
    for (int j = 0; j < 4; ++j)
      C[(size_t)(m0 + ty * 8 + i) * N + n0 + tx * 4 + j] = acc[i][j];
}

// ------------- RoPE fp32, NEGATED ANGLE: x0' = x0*c + x1*s ; x1' = x1*c - x0*s -------------
// (= rotate_half -> cat([x2, -x1]), or q*cos - rotate_half(q)*sin, or sin/cos swap)
__global__ void k_rope_f32(float* __restrict__ Q, float* __restrict__ Kv,
                           const int* __restrict__ pos) {
  int idx = blockIdx.x * blockDim.x + threadIdx.x;
  int j = idx & 63;
  int hh = (idx >> 6) % (NH + NKV);
  int s = idx / (64 * (NH + NKV));
  float p = (float)pos[s];
  float invf = exp2f(-(float)j * (13.287712379549449f / 64.0f));  // 10000^(-j/64)
  float ang = p * invf;
  float c, sn;
  sincosf(ang, &c, &sn);
  float* base = (hh < NH) ? (Q + (size_t)s * HID + hh * HD)
                          : (Kv + (size_t)s * KVDIM + (hh - NH) * HD);
  float x0 = base[j];
  float x1 = base[j + 64];
  base[j]      = x0 * c + x1 * sn;   // R(-angle): mutation under test
  base[j + 64] = x1 * c - x0 * sn;
}

// ---------------- scalar fp32 flash attention (causal, GQA) ----------------
__global__ __launch_bounds__(256) void k_attn_f32(const float* __restrict__ Q,
                                                  const float* __restrict__ K,
                                                  const float* __restrict__ V,
                                                  float* __restrict__ O) {
  __shared__ float Qs[32][129];
  __shared__ float Ks[32][129];
  __shared__ float Vs[32][129];
  __shared__ float Pl[32][32];
  __shared__ float Mx[32][8];
  __shared__ float Lx[32][8];
  const int tid = threadIdx.x;
  const int r = tid >> 3, sub = tid & 7;
  const int qb = blockIdx.x, h = blockIdx.y, kvh = h >> 2;
  const int q0 = qb * 32;

#pragma unroll
  for (int q = 0; q < 4; ++q) {
    int c = q * 256 + tid;
    int row = c >> 5, ck = (c & 31) * 4;
    float4 v = *(const float4*)(Q + (size_t)(q0 + row) * HID + h * HD + ck);
    Qs[row][ck] = v.x; Qs[row][ck + 1] = v.y; Qs[row][ck + 2] = v.z; Qs[row][ck + 3] = v.w;
  }

  float o[16];
#pragma unroll
  for (int k = 0; k < 16; ++k) o[k] = 0.f;
  float m = -1e30f, l = 0.f;

  for (int kv0 = 0; kv0 < q0 + 32; kv0 += 32) {
    __syncthreads();
#pragma unroll
    for (int q = 0; q < 4; ++q) {
      int c = q * 256 + tid;
      int row = c >> 5, ck = (c & 31) * 4;
      float4 kv = *(const float4*)(K + (size_t)(kv0 + row) * KVDIM + kvh * HD + ck);
      Ks[row][ck] = kv.x; Ks[row][ck + 1] = kv.y; Ks[row][ck + 2] = kv.z; Ks[row][ck + 3] = kv.w;
      float4 vv = *(const float4*)(V + (size_t)(kv0 + row) * KVDIM + kvh * HD + ck);
      Vs[row][ck] = vv.x; Vs[row][ck + 1] = vv.y; Vs[row][ck + 2] = vv.z; Vs[row][ck + 3] = vv.w;
    }
    __syncthreads();

    float s4[4];
    float lmax = -1e30f;
#pragma unroll
    for (int jj = 0; jj < 4; ++jj) {
      int j = sub * 4 + jj;
      float acc = 0.f;
      for (int d = 0; d < HD; ++d) acc = fmaf(Qs[r][d], Ks[j][d], acc);
      s4[jj] = (kv0 + j <= q0 + r) ? acc * 0.08838834764831845f : -1e30f;
      lmax = fmaxf(lmax, s4[jj]);
    }
    Mx[r][sub] = lmax;
    __syncthreads();
    float tmax = Mx[r][0];
#pragma unroll
    for (int i = 1; i < 8; ++i) tmax = fmaxf(tmax, Mx[r][i]);
    float m_new = fmaxf(m, tmax);
    float scal = __expf(m - m_new);
    m = m_new;
    float psum = 0.f;
#pragma unroll
    for (int jj = 0; jj < 4; ++jj) {
      float p = __expf(s4[jj] - m_new);
      Pl[r][sub * 4 + jj] = p;
      psum += p;
    }
    Lx[r][sub] = psum;
    __syncthreads();
    float tl = Lx[r][0];
#pragma unroll
    for (int i = 1; i < 8; ++i) tl += Lx[r][i];
    l = l * scal + tl;
#pragma unroll
    for (int k = 0; k < 16; ++k) o[k] *= scal;

    for (int j = 0; j < 32; ++j) {
      float p = Pl[r][j];
#pragma unroll
      for (int k = 0; k < 16; ++k) o[k] = fmaf(p, Vs[j][sub * 16 + k], o[k]);
    }
  }

  float inv_l = 1.f / l;
#pragma unroll
  for (int k = 0; k < 16; ++k)
    O[(size_t)(q0 + r) * HID + h * HD + sub * 16 + k] = o[k] * inv_l;
}

// ---------------- launch ----------------
// HYPOTHESIS (quantitative fit): ref's RoPE rotates by the NEGATED angle
// (rotate_half sign moved / sin-cos swap — all score-equivalent).
extern "C" void kernel_launch(void* const* d_in, const int* in_sizes, int n_in,
                              void* d_out, int out_size, void* d_ws, size_t ws_size,
                              hipStream_t stream) {
  const float* X  = (const float*)d_in[0];
  const float* Wq = (const float*)d_in[1];
  const float* Wk = (const float*)d_in[2];
  const float* Wv = (const float*)d_in[3];
  const float* Wo = (const float*)d_in[4];
  const int* pos  = (const int*)d_in[5];
  char* ws = (char*)d_ws;

  float* Qf  = (float*)(ws + 0);          // 33.55 MB
  float* Kf  = (float*)(ws + 33554432);   //  8.39 MB
  float* Vf  = (float*)(ws + 41943040);   //  8.39 MB
  float* AOf = (float*)(ws + 50331648);   // 33.55 MB

  k_gemm_f32<<<dim3(16, 64), 256, 0, stream>>>(X, Wq, Qf, S_LEN, HID, HID);
  k_gemm_f32<<<dim3(16, 16), 256, 0, stream>>>(X, Wk, Kf, S_LEN, KVDIM, HID);
  k_gemm_f32<<<dim3(16, 16), 256, 0, stream>>>(X, Wv, Vf, S_LEN, KVDIM, HID);

  k_rope_f32<<<(S_LEN * (NH + NKV) * 64) / 256, 256, 0, stream>>>(Qf, Kf, pos);

  k_attn_f32<<<dim3(S_LEN / 32, NH), 256, 0, stream>>>(Qf, Kf, Vf, AOf);

  k_gemm_f32<<<dim3(16, 64), 256, 0, stream>>>(AOf, Wo, (float*)d_out, S_LEN, HID, HID);
}

// Round 22
// 661.799 us; speedup vs baseline: 14.2501x; 14.2501x over previous
//
#include <hip/hip_runtime.h>
#include <hip/hip_fp16.h>

#define S_LEN 2048
#define HID   4096
#define NH    32
#define NKV   8
#define HD    128

using half8 = __attribute__((ext_vector_type(8))) _Float16;
using f32x4 = __attribute__((ext_vector_type(4))) float;

__device__ __forceinline__ void async16(const void* g, void* l) {
  __builtin_amdgcn_global_load_lds(
      (const __attribute__((address_space(1))) unsigned int*)g,
      (__attribute__((address_space(3))) unsigned int*)l, 16, 0, 0);
}

// ---------------- fp32 -> fp16 convert ----------------
__global__ void k_cvt(const float* __restrict__ in, __half* __restrict__ out, int n) {
  int idx = blockIdx.x * blockDim.x + threadIdx.x;
  int stride = gridDim.x * blockDim.x;
  for (int i = idx * 4; i < n; i += stride * 4) {
    float4 v = *(const float4*)(in + i);
    __half2* o = (__half2*)(out + i);
    o[0] = __floats2half2_rn(v.x, v.y);
    o[1] = __floats2half2_rn(v.z, v.w);
  }
}

// ---------------- GEMM: C[m][n] = sum_k A[m][k]*B[n][k] ----------------
// A:[M][K] f16, B:[N][K] f16. 128x128 tile, BK=32, 4 waves.
// mode 0: C half [M][N]; mode 1: C float [M][N]; mode 2: C half transposed [N][M].
__global__ __launch_bounds__(256) void k_gemm(const __half* __restrict__ A,
                                              const __half* __restrict__ B,
                                              __half* __restrict__ Ch,
                                              float* __restrict__ Cf,
                                              int M, int N, int K, int mode) {
  __shared__ __half As[128 * 32];
  __shared__ __half Bs[128 * 32];
  const int tid = threadIdx.x;
  const int lane = tid & 63;
  const int wave = tid >> 6;
  const int m0 = blockIdx.x * 128, n0 = blockIdx.y * 128;
  const int wm = (wave >> 1) * 64, wn = (wave & 1) * 64;
  const int lr = lane & 15, lg = lane >> 4;

  f32x4 acc[4][4];
#pragma unroll
  for (int i = 0; i < 4; ++i)
#pragma unroll
    for (int j = 0; j < 4; ++j) acc[i][j] = f32x4{0.f, 0.f, 0.f, 0.f};

  for (int kt = 0; kt < K; kt += 32) {
    __syncthreads();
#pragma unroll
    for (int q = 0; q < 2; ++q) {
      int chunk = q * 256 + wave * 64 + lane;
      int row = chunk >> 2, kc = chunk & 3;
      async16(A + (size_t)(m0 + row) * K + kt + kc * 8,
              (char*)As + q * 4096 + wave * 1024);
      async16(B + (size_t)(n0 + row) * K + kt + kc * 8,
              (char*)Bs + q * 4096 + wave * 1024);
    }
    __syncthreads();

    half8 af[4], bfr[4];
#pragma unroll
    for (int i = 0; i < 4; ++i) {
      af[i]  = *(const half8*)((const char*)As + (wm + i * 16 + lr) * 64 + lg * 16);
      bfr[i] = *(const half8*)((const char*)Bs + (wn + i * 16 + lr) * 64 + lg * 16);
    }
#pragma unroll
    for (int i = 0; i < 4; ++i)
#pragma unroll
      for (int j = 0; j < 4; ++j)
        acc[i][j] = __builtin_amdgcn_mfma_f32_16x16x32_f16(af[i], bfr[j], acc[i][j], 0, 0, 0);
  }

#pragma unroll
  for (int i = 0; i < 4; ++i)
#pragma unroll
    for (int j = 0; j < 4; ++j) {
      int col = n0 + wn + j * 16 + lr;
#pragma unroll
      for (int r = 0; r < 4; ++r) {
        int row = m0 + wm + i * 16 + lg * 4 + r;
        if (mode == 1)      Cf[(size_t)row * N + col] = acc[i][j][r];
        else if (mode == 2) Ch[(size_t)col * M + row] = __float2half(acc[i][j][r]);
        else                Ch[(size_t)row * N + col] = __float2half(acc[i][j][r]);
      }
    }
}

// ---------------- RoPE, NEGATED ANGLE (in-place on fp16 Q and K) ----------------
// x0' = x0*c + x1*s ; x1' = x1*c - x0*s   (verified semantics, R21)
__global__ void k_rope(__half* __restrict__ Q, __half* __restrict__ Kv,
                       const int* __restrict__ pos) {
  int idx = blockIdx.x * blockDim.x + threadIdx.x;
  int j = idx & 63;
  int hh = (idx >> 6) % (NH + NKV);
  int s = idx / (64 * (NH + NKV));
  float p = (float)pos[s];
  float invf = exp2f(-(float)j * (13.287712379549449f / 64.0f));  // 10000^(-j/64)
  float ang = p * invf;
  float c, sn;
  sincosf(ang, &c, &sn);
  __half* base = (hh < NH) ? (Q + (size_t)s * HID + hh * HD)
                           : (Kv + (size_t)s * (NKV * HD) + (hh - NH) * HD);
  float x0 = __half2float(base[j]);
  float x1 = __half2float(base[j + 64]);
  base[j]      = __float2half(x0 * c + x1 * sn);
  base[j + 64] = __float2half(x1 * c - x0 * sn);
}

// ---------------- Flash attention (causal, GQA), fp16 MFMA ----------------
// grid (S/64, NH); 4 waves; wave w owns q rows [qb*64+w*16, +16).
// Vt pre-transposed: Vt[(kvh*128+d)*S_LEN + s].
__global__ __launch_bounds__(256) void k_attn(const __half* __restrict__ Q,
                                              const __half* __restrict__ K,
                                              const __half* __restrict__ Vt,
                                              __half* __restrict__ O) {
  __shared__ char Ks[64 * 256];   // [64 kv][128 d], 16B-chunk XOR-swz by (row&7)
  __shared__ char Vs[128 * 128];  // [128 d][64 kv], 16B-chunk XOR-swz by (row&7)
  __shared__ char Ps[4][2048];    // per-wave P [16 q][64 kv] f16
  const int tid = threadIdx.x, lane = tid & 63, wave = tid >> 6;
  const int qb = blockIdx.x, h = blockIdx.y;
  const int kvh = h >> 2;
  const int q0 = qb * 64 + wave * 16;
  const int lr = lane & 15, lg = lane >> 4;

  half8 qf[4];
#pragma unroll
  for (int kc = 0; kc < 4; ++kc)
    qf[kc] = *(const half8*)(Q + (size_t)(q0 + lr) * HID + h * HD + kc * 32 + lg * 8);

  float m_r[4], l_r[4];
  f32x4 oa[8];
#pragma unroll
  for (int r = 0; r < 4; ++r) { m_r[r] = -1e30f; l_r[r] = 0.f; }
#pragma unroll
  for (int t8 = 0; t8 < 8; ++t8) oa[t8] = f32x4{0.f, 0.f, 0.f, 0.f};

  const int kv_end = qb * 64 + 64;
  for (int kv0 = 0; kv0 < kv_end; kv0 += 64) {
    __syncthreads();
#pragma unroll
    for (int q = 0; q < 4; ++q) {
      int chunk = q * 256 + tid;
      int row = chunk >> 4, ck = chunk & 15;
      uint4 d = *(const uint4*)(K + (size_t)(kv0 + row) * (NKV * HD) + kvh * HD + ck * 8);
      *(uint4*)(Ks + row * 256 + (((ck ^ (row & 7))) << 4)) = d;
    }
#pragma unroll
    for (int q = 0; q < 4; ++q) {
      int chunk = q * 256 + tid;
      int row = chunk >> 3, ck = chunk & 7;
      uint4 d = *(const uint4*)(Vt + (size_t)(kvh * HD + row) * S_LEN + kv0 + ck * 8);
      *(uint4*)(Vs + row * 128 + (((ck ^ (row & 7))) << 4)) = d;
    }
    __syncthreads();

    // S = Q K^T ; lane holds S[lg*4+r][c*16+lr]
    f32x4 sc[4];
#pragma unroll
    for (int c = 0; c < 4; ++c) sc[c] = f32x4{0.f, 0.f, 0.f, 0.f};
#pragma unroll
    for (int c = 0; c < 4; ++c) {
      int row = c * 16 + lr;
#pragma unroll
      for (int kc = 0; kc < 4; ++kc) {
        int ck = (kc * 4 + lg) ^ (row & 7);
        half8 kf = *(const half8*)(Ks + row * 256 + ck * 16);
        sc[c] = __builtin_amdgcn_mfma_f32_16x16x32_f16(qf[kc], kf, sc[c], 0, 0, 0);
      }
    }

    float pv[4][4];
#pragma unroll
    for (int c = 0; c < 4; ++c) {
      int kvg = kv0 + c * 16 + lr;
#pragma unroll
      for (int r = 0; r < 4; ++r) {
        int qg = q0 + lg * 4 + r;
        float v = sc[c][r] * 0.08838834764831845f;
        pv[c][r] = (kvg <= qg) ? v : -1e30f;
      }
    }
#pragma unroll
    for (int r = 0; r < 4; ++r) {
      float t = fmaxf(fmaxf(pv[0][r], pv[1][r]), fmaxf(pv[2][r], pv[3][r]));
      t = fmaxf(t, __shfl_xor(t, 1));
      t = fmaxf(t, __shfl_xor(t, 2));
      t = fmaxf(t, __shfl_xor(t, 4));
      t = fmaxf(t, __shfl_xor(t, 8));
      float mnew = fmaxf(m_r[r], t);
      float scal = __expf(m_r[r] - mnew);
      m_r[r] = mnew;
      float ps = 0.f;
#pragma unroll
      for (int c = 0; c < 4; ++c) {
        float p = __expf(pv[c][r] - mnew);
        pv[c][r] = p;
        ps += p;
      }
      ps += __shfl_xor(ps, 1);
      ps += __shfl_xor(ps, 2);
      ps += __shfl_xor(ps, 4);
      ps += __shfl_xor(ps, 8);
      l_r[r] = l_r[r] * scal + ps;
#pragma unroll
      for (int t8 = 0; t8 < 8; ++t8) oa[t8][r] *= scal;
    }

    // P -> per-wave LDS to reach MFMA A-fragment layout
#pragma unroll
    for (int c = 0; c < 4; ++c)
#pragma unroll
      for (int r = 0; r < 4; ++r)
        *(__half*)(Ps[wave] + (lg * 4 + r) * 128 + (c * 16 + lr) * 2) = __float2half(pv[c][r]);
    __syncthreads();
    half8 pa[2];
#pragma unroll
    for (int kc = 0; kc < 2; ++kc)
      pa[kc] = *(const half8*)(Ps[wave] + lr * 128 + kc * 64 + lg * 16);

    // O += P V
#pragma unroll
    for (int t8 = 0; t8 < 8; ++t8) {
#pragma unroll
      for (int kc = 0; kc < 2; ++kc) {
        int dd = t8 * 16 + lr;
        int ck = (kc * 4 + lg) ^ (dd & 7);
        half8 vf = *(const half8*)(Vs + dd * 128 + ck * 16);
        oa[t8] = __builtin_amdgcn_mfma_f32_16x16x32_f16(pa[kc], vf, oa[t8], 0, 0, 0);
      }
    }
  }

#pragma unroll
  for (int t8 = 0; t8 < 8; ++t8)
#pragma unroll
    for (int r = 0; r < 4; ++r) {
      float o = oa[t8][r] / l_r[r];
      O[(size_t)(q0 + lg * 4 + r) * HID + h * HD + t8 * 16 + lr] = __float2half(o);
    }
}

// ---------------- launch ----------------
extern "C" void kernel_launch(void* const* d_in, const int* in_sizes, int n_in,
                              void* d_out, int out_size, void* d_ws, size_t ws_size,
                              hipStream_t stream) {
  const float* X  = (const float*)d_in[0];
  const float* Wq = (const float*)d_in[1];
  const float* Wk = (const float*)d_in[2];
  const float* Wv = (const float*)d_in[3];
  const float* Wo = (const float*)d_in[4];
  const int* pos  = (const int*)d_in[5];
  char* ws = (char*)d_ws;

  __half* Xh   = (__half*)(ws + 0);          // 16.78 MB (reused as AOh)
  __half* Wbuf = (__half*)(ws + 16777216);   // 33.55 MB (Wq, then Wo)
  __half* Wkh  = (__half*)(ws + 50331648);   //  8.39 MB
  __half* Wvh  = (__half*)(ws + 58720256);   //  8.39 MB
  __half* Qh   = (__half*)(ws + 67108864);   // 16.78 MB
  __half* Kh   = (__half*)(ws + 83886080);   //  4.19 MB
  __half* Vth  = (__half*)(ws + 88080384);   //  4.19 MB (transposed V: [NKV*HD][S])
  __half* AOh  = Xh;                         // alias: X dead after V-GEMM

  k_cvt<<<2048, 256, 0, stream>>>(X,  Xh,   S_LEN * HID);
  k_cvt<<<2048, 256, 0, stream>>>(Wq, Wbuf, HID * HID);
  k_cvt<<<2048, 256, 0, stream>>>(Wk, Wkh,  NKV * HD * HID);
  k_cvt<<<2048, 256, 0, stream>>>(Wv, Wvh,  NKV * HD * HID);

  k_gemm<<<dim3(16, 32), 256, 0, stream>>>(Xh, Wbuf, Qh, nullptr, S_LEN, HID, HID, 0);
  k_gemm<<<dim3(16, 8),  256, 0, stream>>>(Xh, Wkh,  Kh, nullptr, S_LEN, NKV * HD, HID, 0);
  k_gemm<<<dim3(16, 8),  256, 0, stream>>>(Xh, Wvh,  Vth, nullptr, S_LEN, NKV * HD, HID, 2);

  // Wq dead; convert Wo into same buffer (stream-ordered after Q-GEMM)
  k_cvt<<<2048, 256, 0, stream>>>(Wo, Wbuf, HID * HID);

  k_rope<<<(S_LEN * (NH + NKV) * 64) / 256, 256, 0, stream>>>(Qh, Kh, pos);

  k_attn<<<dim3(S_LEN / 64, NH), 256, 0, stream>>>(Qh, Kh, Vth, AOh);

  k_gemm<<<dim3(16, 32), 256, 0, stream>>>(AOh, Wbuf, nullptr, (float*)d_out, S_LEN, HID, HID, 1);
}

// Round 23
// 657.199 us; speedup vs baseline: 14.3498x; 1.0070x over previous
//
#include <hip/hip_runtime.h>
#include <hip/hip_fp16.h>

#define S_LEN 2048
#define HID   4096
#define NH    32
#define NKV   8
#define HD    128

using half8 = __attribute__((ext_vector_type(8))) _Float16;
using f32x4 = __attribute__((ext_vector_type(4))) float;

__device__ __forceinline__ void async16(const void* g, void* l) {
  __builtin_amdgcn_global_load_lds(
      (const __attribute__((address_space(1))) unsigned int*)g,
      (__attribute__((address_space(3))) unsigned int*)l, 16, 0, 0);
}

// ---------------- fp32 -> fp16 convert ----------------
__global__ void k_cvt(const float* __restrict__ in, __half* __restrict__ out, int n) {
  int idx = blockIdx.x * blockDim.x + threadIdx.x;
  int stride = gridDim.x * blockDim.x;
  for (int i = idx * 4; i < n; i += stride * 4) {
    float4 v = *(const float4*)(in + i);
    __half2* o = (__half2*)(out + i);
    o[0] = __floats2half2_rn(v.x, v.y);
    o[1] = __floats2half2_rn(v.z, v.w);
  }
}

// ---------------- GEMM: C[m][n] = sum_k A[m][k]*B[n][k] ----------------
__global__ __launch_bounds__(256) void k_gemm(const __half* __restrict__ A,
                                              const __half* __restrict__ B,
                                              __half* __restrict__ Ch,
                                              float* __restrict__ Cf,
                                              int M, int N, int K, int mode) {
  __shared__ __half As[128 * 32];
  __shared__ __half Bs[128 * 32];
  const int tid = threadIdx.x;
  const int lane = tid & 63;
  const int wave = tid >> 6;
  const int m0 = blockIdx.x * 128, n0 = blockIdx.y * 128;
  const int wm = (wave >> 1) * 64, wn = (wave & 1) * 64;
  const int lr = lane & 15, lg = lane >> 4;

  f32x4 acc[4][4];
#pragma unroll
  for (int i = 0; i < 4; ++i)
#pragma unroll
    for (int j = 0; j < 4; ++j) acc[i][j] = f32x4{0.f, 0.f, 0.f, 0.f};

  for (int kt = 0; kt < K; kt += 32) {
    __syncthreads();
#pragma unroll
    for (int q = 0; q < 2; ++q) {
      int chunk = q * 256 + wave * 64 + lane;
      int row = chunk >> 2, kc = chunk & 3;
      async16(A + (size_t)(m0 + row) * K + kt + kc * 8,
              (char*)As + q * 4096 + wave * 1024);
      async16(B + (size_t)(n0 + row) * K + kt + kc * 8,
              (char*)Bs + q * 4096 + wave * 1024);
    }
    __syncthreads();

    half8 af[4], bfr[4];
#pragma unroll
    for (int i = 0; i < 4; ++i) {
      af[i]  = *(const half8*)((const char*)As + (wm + i * 16 + lr) * 64 + lg * 16);
      bfr[i] = *(const half8*)((const char*)Bs + (wn + i * 16 + lr) * 64 + lg * 16);
    }
#pragma unroll
    for (int i = 0; i < 4; ++i)
#pragma unroll
      for (int j = 0; j < 4; ++j)
        acc[i][j] = __builtin_amdgcn_mfma_f32_16x16x32_f16(af[i], bfr[j], acc[i][j], 0, 0, 0);
  }

#pragma unroll
  for (int i = 0; i < 4; ++i)
#pragma unroll
    for (int j = 0; j < 4; ++j) {
      int col = n0 + wn + j * 16 + lr;
#pragma unroll
      for (int r = 0; r < 4; ++r) {
        int row = m0 + wm + i * 16 + lg * 4 + r;
        if (mode == 1)      Cf[(size_t)row * N + col] = acc[i][j][r];
        else if (mode == 2) Ch[(size_t)col * M + row] = __float2half(acc[i][j][r]);
        else                Ch[(size_t)row * N + col] = __float2half(acc[i][j][r]);
      }
    }
}

// ---------------- RoPE, NEGATED ANGLE (verified R21) ----------------
__global__ void k_rope(__half* __restrict__ Q, __half* __restrict__ Kv,
                       const int* __restrict__ pos) {
  int idx = blockIdx.x * blockDim.x + threadIdx.x;
  int j = idx & 63;
  int hh = (idx >> 6) % (NH + NKV);
  int s = idx / (64 * (NH + NKV));
  float p = (float)pos[s];
  float invf = exp2f(-(float)j * (13.287712379549449f / 64.0f));
  float ang = p * invf;
  float c, sn;
  sincosf(ang, &c, &sn);
  __half* base = (hh < NH) ? (Q + (size_t)s * HID + hh * HD)
                           : (Kv + (size_t)s * (NKV * HD) + (hh - NH) * HD);
  float x0 = __half2float(base[j]);
  float x1 = __half2float(base[j + 64]);
  base[j]      = __float2half(x0 * c + x1 * sn);
  base[j + 64] = __float2half(x1 * c - x0 * sn);
}

// ---------------- Flash attention (causal, GQA), fp16 MFMA, balanced+prefetch ----
// grid (16, NH): block x processes q-tiles {31-x, x} (33 KV-tiles total each).
__global__ __launch_bounds__(256) void k_attn(const __half* __restrict__ Q,
                                              const __half* __restrict__ K,
                                              const __half* __restrict__ Vt,
                                              __half* __restrict__ O) {
  __shared__ char Ks[64 * 256];   // [64 kv][128 d], 16B-chunk XOR-swz by (row&7)
  __shared__ char Vs[128 * 128];  // [128 d][64 kv], 16B-chunk XOR-swz by (row&7)
  __shared__ char Ps[4][2304];    // per-wave P [16 q][64 kv] f16, stride 144 (bank-spread)
  const int tid = threadIdx.x, lane = tid & 63, wave = tid >> 6;
  const int xblk = blockIdx.x, h = blockIdx.y;
  const int kvh = h >> 2;
  const int lr = lane & 15, lg = lane >> 4;

  const int r0 = (tid >> 4) & 0;  // (unused; silence none)

#pragma unroll
  for (int seg = 0; seg < 2; ++seg) {
    const int qb = seg ? xblk : (31 - xblk);
    const int q0 = qb * 64 + wave * 16;
    const int kv_end = qb * 64 + 64;

    half8 qf[4];
#pragma unroll
    for (int kc = 0; kc < 4; ++kc)
      qf[kc] = *(const half8*)(Q + (size_t)(q0 + lr) * HID + h * HD + kc * 32 + lg * 8);

    float m_r[4], l_r[4];
    f32x4 oa[8];
#pragma unroll
    for (int r = 0; r < 4; ++r) { m_r[r] = -1e30f; l_r[r] = 0.f; }
#pragma unroll
    for (int t8 = 0; t8 < 8; ++t8) oa[t8] = f32x4{0.f, 0.f, 0.f, 0.f};

    // prefetch registers
    uint4 rk[4], rv[4];
#pragma unroll
    for (int q = 0; q < 4; ++q) {
      int chunk = q * 256 + tid;
      int row = chunk >> 4, ck = chunk & 15;
      rk[q] = *(const uint4*)(K + (size_t)(0 + row) * (NKV * HD) + kvh * HD + ck * 8);
      int rowv = chunk >> 3, ckv = chunk & 7;
      rv[q] = *(const uint4*)(Vt + (size_t)(kvh * HD + rowv) * S_LEN + 0 + ckv * 8);
    }

    for (int kv0 = 0; kv0 < kv_end; kv0 += 64) {
      __syncthreads();  // previous tile's readers done
      // write staged regs -> LDS (swizzled)
#pragma unroll
      for (int q = 0; q < 4; ++q) {
        int chunk = q * 256 + tid;
        int row = chunk >> 4, ck = chunk & 15;
        *(uint4*)(Ks + row * 256 + (((ck ^ (row & 7))) << 4)) = rk[q];
        int rowv = chunk >> 3, ckv = chunk & 7;
        *(uint4*)(Vs + rowv * 128 + (((ckv ^ (rowv & 7))) << 4)) = rv[q];
      }
      __syncthreads();
      // issue next tile's loads early (latency hides under compute below)
      if (kv0 + 64 < kv_end) {
#pragma unroll
        for (int q = 0; q < 4; ++q) {
          int chunk = q * 256 + tid;
          int row = chunk >> 4, ck = chunk & 15;
          rk[q] = *(const uint4*)(K + (size_t)(kv0 + 64 + row) * (NKV * HD) + kvh * HD + ck * 8);
          int rowv = chunk >> 3, ckv = chunk & 7;
          rv[q] = *(const uint4*)(Vt + (size_t)(kvh * HD + rowv) * S_LEN + kv0 + 64 + ckv * 8);
        }
      }

      // S = Q K^T ; lane holds S[lg*4+r][c*16+lr]
      f32x4 sc[4];
#pragma unroll
      for (int c = 0; c < 4; ++c) sc[c] = f32x4{0.f, 0.f, 0.f, 0.f};
#pragma unroll
      for (int c = 0; c < 4; ++c) {
        int row = c * 16 + lr;
#pragma unroll
        for (int kc = 0; kc < 4; ++kc) {
          int ck = (kc * 4 + lg) ^ (row & 7);
          half8 kf = *(const half8*)(Ks + row * 256 + ck * 16);
          sc[c] = __builtin_amdgcn_mfma_f32_16x16x32_f16(qf[kc], kf, sc[c], 0, 0, 0);
        }
      }

      float pv[4][4];
#pragma unroll
      for (int c = 0; c < 4; ++c) {
        int kvg = kv0 + c * 16 + lr;
#pragma unroll
        for (int r = 0; r < 4; ++r) {
          int qg = q0 + lg * 4 + r;
          float v = sc[c][r] * 0.08838834764831845f;
          pv[c][r] = (kvg <= qg) ? v : -1e30f;
        }
      }
#pragma unroll
      for (int r = 0; r < 4; ++r) {
        float t = fmaxf(fmaxf(pv[0][r], pv[1][r]), fmaxf(pv[2][r], pv[3][r]));
        t = fmaxf(t, __shfl_xor(t, 1));
        t = fmaxf(t, __shfl_xor(t, 2));
        t = fmaxf(t, __shfl_xor(t, 4));
        t = fmaxf(t, __shfl_xor(t, 8));
        float mnew = fmaxf(m_r[r], t);
        float scal = __expf(m_r[r] - mnew);
        m_r[r] = mnew;
        float ps = 0.f;
#pragma unroll
        for (int c = 0; c < 4; ++c) {
          float p = __expf(pv[c][r] - mnew);
          pv[c][r] = p;
          ps += p;
        }
        ps += __shfl_xor(ps, 1);
        ps += __shfl_xor(ps, 2);
        ps += __shfl_xor(ps, 4);
        ps += __shfl_xor(ps, 8);
        l_r[r] = l_r[r] * scal + ps;
#pragma unroll
        for (int t8 = 0; t8 < 8; ++t8) oa[t8][r] *= scal;
      }

      // P -> per-wave LDS (stride 144 to spread banks)
#pragma unroll
      for (int c = 0; c < 4; ++c)
#pragma unroll
        for (int r = 0; r < 4; ++r)
          *(__half*)(Ps[wave] + (lg * 4 + r) * 144 + (c * 16 + lr) * 2) = __float2half(pv[c][r]);
      __syncthreads();
      half8 pa[2];
#pragma unroll
      for (int kc = 0; kc < 2; ++kc)
        pa[kc] = *(const half8*)(Ps[wave] + lr * 144 + kc * 64 + lg * 16);

      // O += P V
#pragma unroll
      for (int t8 = 0; t8 < 8; ++t8) {
#pragma unroll
        for (int kc = 0; kc < 2; ++kc) {
          int dd = t8 * 16 + lr;
          int ck = (kc * 4 + lg) ^ (dd & 7);
          half8 vf = *(const half8*)(Vs + dd * 128 + ck * 16);
          oa[t8] = __builtin_amdgcn_mfma_f32_16x16x32_f16(pa[kc], vf, oa[t8], 0, 0, 0);
        }
      }
    }

#pragma unroll
    for (int t8 = 0; t8 < 8; ++t8)
#pragma unroll
      for (int r = 0; r < 4; ++r) {
        float o = oa[t8][r] / l_r[r];
        O[(size_t)(q0 + lg * 4 + r) * HID + h * HD + t8 * 16 + lr] = __float2half(o);
      }
  }
}

// ---------------- launch ----------------
extern "C" void kernel_launch(void* const* d_in, const int* in_sizes, int n_in,
                              void* d_out, int out_size, void* d_ws, size_t ws_size,
                              hipStream_t stream) {
  const float* X  = (const float*)d_in[0];
  const float* Wq = (const float*)d_in[1];
  const float* Wk = (const float*)d_in[2];
  const float* Wv = (const float*)d_in[3];
  const float* Wo = (const float*)d_in[4];
  const int* pos  = (const int*)d_in[5];
  char* ws = (char*)d_ws;

  __half* Xh   = (__half*)(ws + 0);          // 16.78 MB (reused as AOh)
  __half* Wbuf = (__half*)(ws + 16777216);   // 33.55 MB (Wq, then Wo)
  __half* Wkh  = (__half*)(ws + 50331648);   //  8.39 MB
  __half* Wvh  = (__half*)(ws + 58720256);   //  8.39 MB
  __half* Qh   = (__half*)(ws + 67108864);   // 16.78 MB
  __half* Kh   = (__half*)(ws + 83886080);   //  4.19 MB
  __half* Vth  = (__half*)(ws + 88080384);   //  4.19 MB (transposed V: [NKV*HD][S])
  __half* AOh  = Xh;                         // alias: X dead after V-GEMM

  k_cvt<<<2048, 256, 0, stream>>>(X,  Xh,   S_LEN * HID);
  k_cvt<<<2048, 256, 0, stream>>>(Wq, Wbuf, HID * HID);
  k_cvt<<<2048, 256, 0, stream>>>(Wk, Wkh,  NKV * HD * HID);
  k_cvt<<<2048, 256, 0, stream>>>(Wv, Wvh,  NKV * HD * HID);

  k_gemm<<<dim3(16, 32), 256, 0, stream>>>(Xh, Wbuf, Qh, nullptr, S_LEN, HID, HID, 0);
  k_gemm<<<dim3(16, 8),  256, 0, stream>>>(Xh, Wkh,  Kh, nullptr, S_LEN, NKV * HD, HID, 0);
  k_gemm<<<dim3(16, 8),  256, 0, stream>>>(Xh, Wvh,  Vth, nullptr, S_LEN, NKV * HD, HID, 2);

  k_cvt<<<2048, 256, 0, stream>>>(Wo, Wbuf, HID * HID);

  k_rope<<<(S_LEN * (NH + NKV) * 64) / 256, 256, 0, stream>>>(Qh, Kh, pos);

  k_attn<<<dim3(16, NH), 256, 0, stream>>>(Qh, Kh, Vth, AOh);

  k_gemm<<<dim3(16, 32), 256, 0, stream>>>(AOh, Wbuf, nullptr, (float*)d_out, S_LEN, HID, HID, 1);
}